// Round 7
// baseline (551.200 us; speedup 1.0000x reference)
//
#include <hip/hip_runtime.h>
#include <hip/hip_bf16.h>
#include <math.h>

#define DM 1024
#define NH 16
#define DK 64
#define BB 4
#define SS 2048
#define EPSV 1e-6f
#define NE ((size_t)BB * SS * DM)  // 8388608
#define MM ((size_t)DM * DM)       // 1048576
// 0.125 * log2(e): folded into w_q so softmax is a raw exp2
#define QSCALE 0.18033688011112042f

typedef __attribute__((ext_vector_type(8))) short short8;
typedef __attribute__((ext_vector_type(4))) float f32x4;

__device__ inline unsigned short f2bf(float x) {
  unsigned int u = __builtin_bit_cast(unsigned int, x);
  u += 0x7FFF + ((u >> 16) & 1);  // RNE
  return (unsigned short)(u >> 16);
}
__device__ inline ushort4 f2bf4(float4 v) {
  ushort4 r;
  r.x = f2bf(v.x); r.y = f2bf(v.y); r.z = f2bf(v.z); r.w = f2bf(v.w);
  return r;
}

__device__ inline float fexp2(float x) {
#if __has_builtin(__builtin_amdgcn_exp2f)
  return __builtin_amdgcn_exp2f(x);
#else
  return exp2f(x);
#endif
}

// pack 2 f32 -> 1 dword of 2 bf16 (lo=a, hi=b)
__device__ inline unsigned cvtpk_bf16(float a, float b) {
  unsigned r;
  asm("v_cvt_pk_bf16_f32 %0, %1, %2" : "=v"(r) : "v"(a), "v"(b));
  return r;
}

// async global->LDS, 16B per lane; LDS dest = wave-uniform base + lane*16
__device__ inline void gl_lds16(const unsigned short* g, unsigned short* l) {
  __builtin_amdgcn_global_load_lds((const __attribute__((address_space(1))) void*)g,
                                   (__attribute__((address_space(3))) void*)l, 16, 0, 0);
}

// ---- Pre-pass: x tensors f32 -> bf16 (elementwise, float4) ----
__global__ __launch_bounds__(256) void cvt_x_k(const float* __restrict__ xq,
                                               const float* __restrict__ xk,
                                               const float* __restrict__ xv,
                                               unsigned short* __restrict__ oq,
                                               unsigned short* __restrict__ ok,
                                               unsigned short* __restrict__ ov) {
  const size_t NF4 = NE / 4;
  size_t g = (size_t)blockIdx.x * 256 + threadIdx.x;
  int t = (int)(g / NF4);
  size_t i = g - (size_t)t * NF4;
  const float* s = (t == 0) ? xq : (t == 1) ? xk : xv;
  unsigned short* d = (t == 0) ? oq : (t == 1) ? ok : ov;
  float4 v = ((const float4*)s)[i];
  ((ushort4*)d)[i] = f2bf4(v);
}

// ---- Pre-pass: W[k][n] f32 -> WT[n][k] bf16 (LDS transpose); w_q gets QSCALE ----
__global__ __launch_bounds__(256) void cvt_wT_k(const float* __restrict__ w0,
                                                const float* __restrict__ w1,
                                                const float* __restrict__ w2,
                                                const float* __restrict__ w3,
                                                unsigned short* __restrict__ o0,
                                                unsigned short* __restrict__ o1,
                                                unsigned short* __restrict__ o2,
                                                unsigned short* __restrict__ o3) {
  __shared__ float t[32][33];
  int z = blockIdx.z;
  const float* w = (z == 0) ? w0 : (z == 1) ? w1 : (z == 2) ? w2 : w3;
  unsigned short* o = (z == 0) ? o0 : (z == 1) ? o1 : (z == 2) ? o2 : o3;
  float sc = (z == 0) ? QSCALE : 1.0f;
  int n0 = blockIdx.x * 32, k0 = blockIdx.y * 32;
  int tx = threadIdx.x & 31, ty = threadIdx.x >> 5;
#pragma unroll
  for (int s = 0; s < 4; ++s) t[ty + s * 8][tx] = w[(size_t)(k0 + ty + s * 8) * DM + n0 + tx];
  __syncthreads();
#pragma unroll
  for (int s = 0; s < 4; ++s)
    o[(size_t)(n0 + ty + s * 8) * DM + k0 + tx] = f2bf(t[tx][ty + s * 8] * sc);
}

// ---- Pre-pass: pack int32 mask -> 1 bit ----
__global__ __launch_bounds__(256) void maskbits_k(const int* __restrict__ mask,
                                                  unsigned long long* __restrict__ bm) {
  const int total = BB * SS * (SS / 64);
  int lane = threadIdx.x & 63;
  int wid = (blockIdx.x * 256 + threadIdx.x) >> 6;
  int nw = (gridDim.x * 256) >> 6;
  for (int w = wid; w < total; w += nw) {
    int v = mask[(size_t)w * 64 + lane];
    unsigned long long bal = __ballot(v != 0);
    if (lane == 0) bm[w] = bal;
  }
}

// ---- V pack: Vb[B,S,NH*DK] -> VP[b][h][kt][e], e in R4-proven VB element order:
// e = p*2048 + o*128 + vcp*16 + hi*8 + vjh*4 + i  holds
// V[kt*64 + p*32 + 16*vjh + 4*(o&3) + i][(o>>2)*16 + vcp*2 + hi]  (cols within head).
// Thread tid writes e = p*2048 + tid*8 + j: one column gather of 8 rows from LDS.
__global__ __launch_bounds__(256) void vpack_k(const unsigned short* __restrict__ Vb,
                                               unsigned short* __restrict__ VP) {
  __shared__ unsigned short t[64][72];
  int b = blockIdx.z, h = blockIdx.y, kt = blockIdx.x;
  int tid = threadIdx.x;
#pragma unroll
  for (int p = 0; p < 2; ++p) {
    int idx = p * 256 + tid;
    int r = idx >> 3, cch = (idx & 7) * 8;
    short8 v = *(const short8*)&Vb[((size_t)b * SS + kt * 64 + r) * DM + h * DK + cch];
    *(short8*)&t[r][cch] = v;
  }
  __syncthreads();
  int o = tid >> 4, w0 = o & 3;
  int dcol = (o >> 2) * 16 + ((tid & 15) >> 1) * 2 + (tid & 1);
  unsigned short* dst =
      VP + (((size_t)b * NH + h) * (SS / 64) + kt) * 4096 + (size_t)tid * 8;
#pragma unroll
  for (int p = 0; p < 2; ++p) {
    union { short8 v; unsigned short u[8]; } pk;
#pragma unroll
    for (int j = 0; j < 8; ++j) {
      int srow = p * 32 + 16 * (j >> 2) + 4 * w0 + (j & 3);
      pk.u[j] = t[srow][dcol];
    }
    *(short8*)&dst[p * 2048] = pk.v;
  }
}

// ---- m97-style MFMA GEMM: C = A[M,K] @ WT[N,K]^T, bf16 in, 128x128 tile, BK=32.
template <bool BF16OUT>
__global__ __launch_bounds__(256) void gemm_lds_k(const unsigned short* __restrict__ Abase,
                                                  const unsigned short* __restrict__ WTbase,
                                                  void* __restrict__ Cv, int M, int N, int K,
                                                  size_t zA, size_t zW, size_t zC) {
  __shared__ __align__(16) unsigned short As[128 * 32];
  __shared__ __align__(16) unsigned short Bs[128 * 32];
  const unsigned short* A = Abase + (size_t)blockIdx.z * zA;
  const unsigned short* WT = WTbase + (size_t)blockIdx.z * zW;
  int bm = blockIdx.y * 128, bn = blockIdx.x * 128;
  int tid = threadIdx.x, lane = tid & 63, w = tid >> 6;
  int quad = lane >> 4, c = lane & 15, wx = w & 1, wy = w >> 1;

  f32x4 acc[4][4];
#pragma unroll
  for (int mt = 0; mt < 4; ++mt)
#pragma unroll
    for (int nt = 0; nt < 4; ++nt)
#pragma unroll
      for (int r = 0; r < 4; ++r) acc[mt][nt][r] = 0.f;

  int srow = lane >> 2, scol = (lane & 3) * 8;
  const unsigned short* Ag = A + (size_t)(bm + w * 32 + srow) * K + scol;
  const unsigned short* Bg = WT + (size_t)(bn + w * 32 + srow) * K + scol;
  unsigned short* Al = &As[w * 32 * 32];
  unsigned short* Bl = &Bs[w * 32 * 32];

  for (int k0 = 0; k0 < K; k0 += 32) {
    gl_lds16(Ag + k0, Al);
    gl_lds16(Ag + (size_t)16 * K + k0, Al + 16 * 32);
    gl_lds16(Bg + k0, Bl);
    gl_lds16(Bg + (size_t)16 * K + k0, Bl + 16 * 32);
    __syncthreads();  // drains vmcnt -> LDS valid
    short8 af[4], bf[4];
#pragma unroll
    for (int mt = 0; mt < 4; ++mt) af[mt] = *(const short8*)&As[(wy * 64 + mt * 16 + c) * 32 + quad * 8];
#pragma unroll
    for (int nt = 0; nt < 4; ++nt) bf[nt] = *(const short8*)&Bs[(wx * 64 + nt * 16 + c) * 32 + quad * 8];
#pragma unroll
    for (int mt = 0; mt < 4; ++mt)
#pragma unroll
      for (int nt = 0; nt < 4; ++nt)
        acc[mt][nt] = __builtin_amdgcn_mfma_f32_16x16x32_bf16(af[mt], bf[nt], acc[mt][nt], 0, 0, 0);
    __syncthreads();
  }
#pragma unroll
  for (int mt = 0; mt < 4; ++mt)
#pragma unroll
    for (int nt = 0; nt < 4; ++nt)
#pragma unroll
      for (int r = 0; r < 4; ++r) {
        size_t idx = (size_t)blockIdx.z * zC +
                     (size_t)(bm + wy * 64 + mt * 16 + quad * 4 + r) * N + bn + wx * 64 + nt * 16 + c;
        if (BF16OUT)
          ((unsigned short*)Cv)[idx] = f2bf(acc[mt][nt][r]);
        else
          ((float*)Cv)[idx] = acc[mt][nt][r];
      }
}

// ---- MFMA flash attention, swapped-QK^T, double-buffered gl_lds staging.
// K LDS: row-major [64][8 chunks of 8], chunk XOR (cc ^ (row&7)) pre-applied to
//        the GLOBAL source (R4-verified); ds_read_b128 applies the same XOR.
// V via VP (pre-packed, R4-proven VB element order): staging is 2 contiguous
//        gl_lds16; PV B-fragment is ONE ds_read_b128 at the R4-proven address.
// Mask word for tile kt+1 prefetched during tile kt (barrier drain hides it).
// Row-sum via ones-MFMA: lacc rows (quad*4+r) align with accO rows.
__global__ __launch_bounds__(256) void attn_mfma_k(const unsigned short* __restrict__ Q,
                                                   const unsigned short* __restrict__ Kg,
                                                   const unsigned short* __restrict__ VP,
                                                   const unsigned long long* __restrict__ bm,
                                                   unsigned short* __restrict__ O) {
  __shared__ __align__(16) unsigned short Ks[2][64 * 64];
  __shared__ __align__(16) unsigned short Vs[2][64 * 64];
  int b = blockIdx.z, h = blockIdx.y, q0 = blockIdx.x * 64;
  int tid = threadIdx.x, lane = tid & 63, w = tid >> 6;
  int quad = lane >> 4, c = lane & 15;

  short8 qf[2];
  {
    const unsigned short* qp = Q + ((size_t)b * SS + q0 + w * 16 + c) * DM + h * DK + quad * 8;
    qf[0] = *(const short8*)qp;
    qf[1] = *(const short8*)(qp + 32);
  }
  const unsigned long long* bp = bm + ((size_t)b * SS + q0 + w * 16 + c) * (SS / 64);
  const int shq = quad * 4;

  short8 ones8;
#pragma unroll
  for (int j = 0; j < 8; ++j) ones8[j] = (short)0x3F80;  // bf16 1.0

  f32x4 accO[4], lacc;
#pragma unroll
  for (int r = 0; r < 4; ++r) lacc[r] = 0.f;
#pragma unroll
  for (int dt = 0; dt < 4; ++dt)
#pragma unroll
    for (int r = 0; r < 4; ++r) accO[dt][r] = 0.f;

  // K staging source (R4-verified): chunk n=tid (+256): row n>>3, grp (n&7)^(row&7)
  int kr = tid >> 3;
  int scc = (tid & 7) ^ (kr & 7);
  const unsigned short* pK0 = Kg + ((size_t)b * SS + kr) * DM + h * DK + scc * 8;
  const unsigned short* pK1 = pK0 + (size_t)32 * DM;
  // VP staging source: contiguous; thread tid -> elems tid*8 (+2048), advance 4096/tile
  const unsigned short* pV0 =
      VP + ((size_t)b * NH + h) * (SS / 64) * 4096 + (size_t)tid * 8;
  const unsigned short* pV1 = pV0 + 2048;

  // QK fragment elem offsets (row c + nt*16; row&7 == c&7): logical chunk g -> g^(c&7)
  const int kfo0 = c * 64 + ((quad ^ (c & 7)) * 8);
  const int kfo1 = c * 64 + (((4 + quad) ^ (c & 7)) * 8);
  // PV fragment base (R4-proven): row (pkt*4+dt)*4+quad, col c
  const int vfbase = quad * 128 + c * 8;

  const int NT = SS / 64;

  // prologue: stage tile 0 into buf 0; preload mask word for tile 0
  gl_lds16(pK0, &Ks[0][w * 512]);
  gl_lds16(pK1, &Ks[0][2048 + w * 512]);
  gl_lds16(pV0, &Vs[0][w * 512]);
  gl_lds16(pV1, &Vs[0][2048 + w * 512]);
  pK0 += (size_t)64 * DM; pK1 += (size_t)64 * DM;
  pV0 += 4096; pV1 += 4096;
  unsigned long long mw = bp[0];

  auto tile = [&](int buf, int kt) {
    __syncthreads();  // drains vmcnt: tile kt ready; all waves done with buf^1
    if (kt + 1 < NT) {
      gl_lds16(pK0, &Ks[buf ^ 1][w * 512]);
      gl_lds16(pK1, &Ks[buf ^ 1][2048 + w * 512]);
      gl_lds16(pV0, &Vs[buf ^ 1][w * 512]);
      gl_lds16(pV1, &Vs[buf ^ 1][2048 + w * 512]);
      pK0 += (size_t)64 * DM; pK1 += (size_t)64 * DM;
      pV0 += 4096; pV1 += 4096;
    }
    // prefetch next tile's mask word (used next iter; next barrier hides latency)
    unsigned long long mw_next = (kt + 1 < NT) ? bp[kt + 1] : 0ull;

    // QK^T swapped: A = K rows, B = Q -> S^T; lane (c,quad) holds S[q=c][k slices]
    f32x4 sacc[4];
#pragma unroll
    for (int nt = 0; nt < 4; ++nt) {
#pragma unroll
      for (int r = 0; r < 4; ++r) sacc[nt][r] = 0.f;
      short8 ka = *(const short8*)&Ks[buf][kfo0 + nt * 1024];
      short8 kb = *(const short8*)&Ks[buf][kfo1 + nt * 1024];
      sacc[nt] = __builtin_amdgcn_mfma_f32_16x16x32_bf16(ka, qf[0], sacc[nt], 0, 0, 0);
      sacc[nt] = __builtin_amdgcn_mfma_f32_16x16x32_bf16(kb, qf[1], sacc[nt], 0, 0, 0);
    }

    // in-register softmax numerator (scores pre-scaled by 0.125*log2e via w_q)
    unsigned long long msh = mw >> shq;
    unsigned mlo = (unsigned)msh, mhi = (unsigned)(msh >> 32);
    unsigned padw[8];
#pragma unroll
    for (int nt = 0; nt < 4; ++nt) {
      unsigned msel = (nt & 2) ? mhi : mlo;
      const int bse = (nt & 1) * 16;
      float pv[4];
#pragma unroll
      for (int r = 0; r < 4; ++r) {
        float ex = fexp2(sacc[nt][r]);
        pv[r] = ((msel >> (bse + r)) & 1u) ? ex : 1.0f;  // masked -> exp(eps) ~ 1
      }
      padw[nt * 2] = cvtpk_bf16(pv[0], pv[1]);
      padw[nt * 2 + 1] = cvtpk_bf16(pv[2], pv[3]);
    }
    mw = mw_next;

    // PV: A = lane-local packed P, B = one b128 per fragment (R4-proven layout)
#pragma unroll
    for (int pkt = 0; pkt < 2; ++pkt) {
      union { unsigned u[4]; short8 s8; } pa;
#pragma unroll
      for (int i = 0; i < 4; ++i) pa.u[i] = padw[pkt * 4 + i];
      lacc = __builtin_amdgcn_mfma_f32_16x16x32_bf16(pa.s8, ones8, lacc, 0, 0, 0);
#pragma unroll
      for (int dt = 0; dt < 4; ++dt) {
        short8 vf = *(const short8*)&Vs[buf][(pkt * 4 + dt) * 512 + vfbase];
        accO[dt] = __builtin_amdgcn_mfma_f32_16x16x32_bf16(pa.s8, vf, accO[dt], 0, 0, 0);
      }
    }
  };

  for (int kt2 = 0; kt2 < NT; kt2 += 2) {
    tile(0, kt2);
    tile(1, kt2 + 1);
  }

  // lacc rows (quad*4+r) align with accO rows: direct normalize, no shuffles
  float inv[4];
#pragma unroll
  for (int r = 0; r < 4; ++r) inv[r] = 1.f / lacc[r];
#pragma unroll
  for (int dt = 0; dt < 4; ++dt)
#pragma unroll
    for (int r = 0; r < 4; ++r) {
      int q = q0 + w * 16 + quad * 4 + r;
      O[((size_t)b * SS + q) * DM + h * DK + dt * 16 + c] = f2bf(accO[dt][r] * inv[r]);
    }
}

// ---- Residual + LayerNorm (ddof=1, eps on std), vectorized ----
__global__ __launch_bounds__(256) void ln_k(const float* __restrict__ P,
                                            const float* __restrict__ X,
                                            const float* __restrict__ gamma,
                                            const float* __restrict__ beta,
                                            float* __restrict__ out) {
  __shared__ float sm[4];
  int row = blockIdx.x, tid = threadIdx.x, w = tid >> 6;
  float4 p = ((const float4*)(P + (size_t)row * DM))[tid];
  float4 x = ((const float4*)(X + (size_t)row * DM))[tid];
  float4 v = make_float4(p.x + x.x, p.y + x.y, p.z + x.z, p.w + x.w);
  float s = (v.x + v.y) + (v.z + v.w);
#pragma unroll
  for (int off = 1; off < 64; off <<= 1) s += __shfl_xor(s, off);
  if ((tid & 63) == 0) sm[w] = s;
  __syncthreads();
  float mean = (sm[0] + sm[1] + sm[2] + sm[3]) * (1.f / DM);
  __syncthreads();
  float dx = v.x - mean, dy = v.y - mean, dz = v.z - mean, dw = v.w - mean;
  float s2 = (dx * dx + dy * dy) + (dz * dz + dw * dw);
#pragma unroll
  for (int off = 1; off < 64; off <<= 1) s2 += __shfl_xor(s2, off);
  if ((tid & 63) == 0) sm[w] = s2;
  __syncthreads();
  float var = (sm[0] + sm[1] + sm[2] + sm[3]) * (1.f / (DM - 1));
  float inv = 1.f / (sqrtf(var) + EPSV);
  float4 g = ((const float4*)gamma)[tid];
  float4 be = ((const float4*)beta)[tid];
  float4 y = make_float4(g.x * dx * inv + be.x, g.y * dy * inv + be.y,
                         g.z * dz * inv + be.z, g.w * dw * inv + be.w);
  ((float4*)(out + (size_t)row * DM))[tid] = y;
}

extern "C" void kernel_launch(void* const* d_in, const int* in_sizes, int n_in,
                              void* d_out, int out_size, void* d_ws, size_t ws_size,
                              hipStream_t stream) {
  const float* xq = (const float*)d_in[0];
  const float* xk = (const float*)d_in[1];
  const float* xv = (const float*)d_in[2];
  const int* mask = (const int*)d_in[3];
  const float* wq = (const float*)d_in[4];
  const float* wk = (const float*)d_in[5];
  const float* wv = (const float*)d_in[6];
  const float* w0 = (const float*)d_in[7];
  const float* gamma = (const float*)d_in[8];
  const float* beta = (const float*)d_in[9];
  float* out = (float*)d_out;

  // ws: [xqb NE][xkb NE][xvb NE][wTq MM][wTk MM][wTv MM][wT0 MM][Qb NE][Kb NE][Vb NE][AOb NE]
  // P (f32, NE) overlays Qb+Kb (dead after attention).
  // VP (bf16, NE) overlays xvb (dead after the QKV GEMM).
  unsigned short* xqb = (unsigned short*)d_ws;
  unsigned short* xkb = xqb + NE;
  unsigned short* xvb = xkb + NE;
  unsigned short* wTq = xvb + NE;
  unsigned short* wTk = wTq + MM;
  unsigned short* wTv = wTk + MM;
  unsigned short* wT0 = wTv + MM;
  unsigned short* Qb = wT0 + MM;
  unsigned short* Kb = Qb + NE;
  unsigned short* Vb = Kb + NE;
  unsigned short* AOb = Vb + NE;
  unsigned short* VPb = xvb;  // overlay
  float* P = (float*)Qb;
  unsigned long long* bm = (unsigned long long*)d_out;  // 2 MB, dead before ln_k writes

  const int M = BB * SS;  // 8192
  cvt_x_k<<<(unsigned)(3 * (NE / 4) / 256), 256, 0, stream>>>(xq, xk, xv, xqb, xkb, xvb);
  cvt_wT_k<<<dim3(32, 32, 4), 256, 0, stream>>>(wq, wk, wv, w0, wTq, wTk, wTv, wT0);
  maskbits_k<<<256, 256, 0, stream>>>(mask, bm);
  gemm_lds_k<true><<<dim3(DM / 128, M / 128, 3), 256, 0, stream>>>(
      xqb, wTq, Qb, M, DM, DM, NE, MM, NE);
  vpack_k<<<dim3(SS / 64, NH, BB), 256, 0, stream>>>(Vb, VPb);
  attn_mfma_k<<<dim3(SS / 64, NH, BB), 256, 0, stream>>>(Qb, Kb, VPb, bm, AOb);
  gemm_lds_k<false><<<dim3(DM / 128, M / 128, 1), 256, 0, stream>>>(
      AOb, wT0, P, M, DM, DM, 0, 0, 0);
  ln_k<<<M, 256, 0, stream>>>(P, xq, gamma, beta, out);
}

// Round 8
// 542.793 us; speedup vs baseline: 1.0155x; 1.0155x over previous
//
#include <hip/hip_runtime.h>
#include <hip/hip_bf16.h>
#include <math.h>

#define DM 1024
#define NH 16
#define DK 64
#define BB 4
#define SS 2048
#define EPSV 1e-6f
#define NE ((size_t)BB * SS * DM)  // 8388608
#define MM ((size_t)DM * DM)       // 1048576
// 0.125 * log2(e): folded into w_q so softmax is a raw exp2
#define QSCALE 0.18033688011112042f

typedef __attribute__((ext_vector_type(8))) short short8;
typedef __attribute__((ext_vector_type(4))) float f32x4;

__device__ inline unsigned short f2bf(float x) {
  unsigned int u = __builtin_bit_cast(unsigned int, x);
  u += 0x7FFF + ((u >> 16) & 1);  // RNE
  return (unsigned short)(u >> 16);
}
__device__ inline ushort4 f2bf4(float4 v) {
  ushort4 r;
  r.x = f2bf(v.x); r.y = f2bf(v.y); r.z = f2bf(v.z); r.w = f2bf(v.w);
  return r;
}

__device__ inline float fexp2(float x) {
#if __has_builtin(__builtin_amdgcn_exp2f)
  return __builtin_amdgcn_exp2f(x);
#else
  return exp2f(x);
#endif
}

// pack 2 f32 -> 1 dword of 2 bf16 (lo=a, hi=b)
__device__ inline unsigned cvtpk_bf16(float a, float b) {
  unsigned r;
  asm("v_cvt_pk_bf16_f32 %0, %1, %2" : "=v"(r) : "v"(a), "v"(b));
  return r;
}

// async global->LDS, 16B per lane; LDS dest = wave-uniform base + lane*16
__device__ inline void gl_lds16(const unsigned short* g, unsigned short* l) {
  __builtin_amdgcn_global_load_lds((const __attribute__((address_space(1))) void*)g,
                                   (__attribute__((address_space(3))) void*)l, 16, 0, 0);
}

// ---- Pre-pass: x tensors f32 -> bf16 (elementwise, float4) ----
__global__ __launch_bounds__(256) void cvt_x_k(const float* __restrict__ xq,
                                               const float* __restrict__ xk,
                                               const float* __restrict__ xv,
                                               unsigned short* __restrict__ oq,
                                               unsigned short* __restrict__ ok,
                                               unsigned short* __restrict__ ov) {
  const size_t NF4 = NE / 4;
  size_t g = (size_t)blockIdx.x * 256 + threadIdx.x;
  int t = (int)(g / NF4);
  size_t i = g - (size_t)t * NF4;
  const float* s = (t == 0) ? xq : (t == 1) ? xk : xv;
  unsigned short* d = (t == 0) ? oq : (t == 1) ? ok : ov;
  float4 v = ((const float4*)s)[i];
  ((ushort4*)d)[i] = f2bf4(v);
}

// ---- Pre-pass: W[k][n] f32 -> WT[n][k] bf16 (LDS transpose); w_q gets QSCALE ----
__global__ __launch_bounds__(256) void cvt_wT_k(const float* __restrict__ w0,
                                                const float* __restrict__ w1,
                                                const float* __restrict__ w2,
                                                const float* __restrict__ w3,
                                                unsigned short* __restrict__ o0,
                                                unsigned short* __restrict__ o1,
                                                unsigned short* __restrict__ o2,
                                                unsigned short* __restrict__ o3) {
  __shared__ float t[32][33];
  int z = blockIdx.z;
  const float* w = (z == 0) ? w0 : (z == 1) ? w1 : (z == 2) ? w2 : w3;
  unsigned short* o = (z == 0) ? o0 : (z == 1) ? o1 : (z == 2) ? o2 : o3;
  float sc = (z == 0) ? QSCALE : 1.0f;
  int n0 = blockIdx.x * 32, k0 = blockIdx.y * 32;
  int tx = threadIdx.x & 31, ty = threadIdx.x >> 5;
#pragma unroll
  for (int s = 0; s < 4; ++s) t[ty + s * 8][tx] = w[(size_t)(k0 + ty + s * 8) * DM + n0 + tx];
  __syncthreads();
#pragma unroll
  for (int s = 0; s < 4; ++s)
    o[(size_t)(n0 + ty + s * 8) * DM + k0 + tx] = f2bf(t[tx][ty + s * 8] * sc);
}

// ---- Pre-pass: pack int32 mask -> 1 bit ----
__global__ __launch_bounds__(256) void maskbits_k(const int* __restrict__ mask,
                                                  unsigned long long* __restrict__ bm) {
  const int total = BB * SS * (SS / 64);
  int lane = threadIdx.x & 63;
  int wid = (blockIdx.x * 256 + threadIdx.x) >> 6;
  int nw = (gridDim.x * 256) >> 6;
  for (int w = wid; w < total; w += nw) {
    int v = mask[(size_t)w * 64 + lane];
    unsigned long long bal = __ballot(v != 0);
    if (lane == 0) bm[w] = bal;
  }
}

// ---- V pack: Vb[B,S,NH*DK] -> VP[b][h][kt][e], e in R4-proven VB element order ----
__global__ __launch_bounds__(256) void vpack_k(const unsigned short* __restrict__ Vb,
                                               unsigned short* __restrict__ VP) {
  __shared__ unsigned short t[64][72];
  int b = blockIdx.z, h = blockIdx.y, kt = blockIdx.x;
  int tid = threadIdx.x;
#pragma unroll
  for (int p = 0; p < 2; ++p) {
    int idx = p * 256 + tid;
    int r = idx >> 3, cch = (idx & 7) * 8;
    short8 v = *(const short8*)&Vb[((size_t)b * SS + kt * 64 + r) * DM + h * DK + cch];
    *(short8*)&t[r][cch] = v;
  }
  __syncthreads();
  int o = tid >> 4, w0 = o & 3;
  int dcol = (o >> 2) * 16 + ((tid & 15) >> 1) * 2 + (tid & 1);
  unsigned short* dst =
      VP + (((size_t)b * NH + h) * (SS / 64) + kt) * 4096 + (size_t)tid * 8;
#pragma unroll
  for (int p = 0; p < 2; ++p) {
    union { short8 v; unsigned short u[8]; } pk;
#pragma unroll
    for (int j = 0; j < 8; ++j) {
      int srow = p * 32 + 16 * (j >> 2) + 4 * w0 + (j & 3);
      pk.u[j] = t[srow][dcol];
    }
    *(short8*)&dst[p * 2048] = pk.v;
  }
}

// ---- m97-style MFMA GEMM + bijective XCD-chunked swizzle (T1).
// grid is always (8, 64, z); cpx = nwg/8.
template <bool BF16OUT>
__global__ __launch_bounds__(256) void gemm_lds_k(const unsigned short* __restrict__ Abase,
                                                  const unsigned short* __restrict__ WTbase,
                                                  void* __restrict__ Cv, int M, int N, int K,
                                                  size_t zA, size_t zW, size_t zC, int cpx) {
  __shared__ __align__(16) unsigned short As[128 * 32];
  __shared__ __align__(16) unsigned short Bs[128 * 32];
  int dlin = (blockIdx.z * gridDim.y + blockIdx.y) * gridDim.x + blockIdx.x;
  int l = (dlin & 7) * cpx + (dlin >> 3);
  int bxs = l & 7, bys = (l >> 3) & 63, bzs = l >> 9;
  const unsigned short* A = Abase + (size_t)bzs * zA;
  const unsigned short* WT = WTbase + (size_t)bzs * zW;
  int bm = bys * 128, bn = bxs * 128;
  int tid = threadIdx.x, lane = tid & 63, w = tid >> 6;
  int quad = lane >> 4, c = lane & 15, wx = w & 1, wy = w >> 1;

  f32x4 acc[4][4];
#pragma unroll
  for (int mt = 0; mt < 4; ++mt)
#pragma unroll
    for (int nt = 0; nt < 4; ++nt)
#pragma unroll
      for (int r = 0; r < 4; ++r) acc[mt][nt][r] = 0.f;

  int srow = lane >> 2, scol = (lane & 3) * 8;
  const unsigned short* Ag = A + (size_t)(bm + w * 32 + srow) * K + scol;
  const unsigned short* Bg = WT + (size_t)(bn + w * 32 + srow) * K + scol;
  unsigned short* Al = &As[w * 32 * 32];
  unsigned short* Bl = &Bs[w * 32 * 32];

  for (int k0 = 0; k0 < K; k0 += 32) {
    gl_lds16(Ag + k0, Al);
    gl_lds16(Ag + (size_t)16 * K + k0, Al + 16 * 32);
    gl_lds16(Bg + k0, Bl);
    gl_lds16(Bg + (size_t)16 * K + k0, Bl + 16 * 32);
    __syncthreads();  // drains vmcnt -> LDS valid
    short8 af[4], bf[4];
#pragma unroll
    for (int mt = 0; mt < 4; ++mt) af[mt] = *(const short8*)&As[(wy * 64 + mt * 16 + c) * 32 + quad * 8];
#pragma unroll
    for (int nt = 0; nt < 4; ++nt) bf[nt] = *(const short8*)&Bs[(wx * 64 + nt * 16 + c) * 32 + quad * 8];
#pragma unroll
    for (int mt = 0; mt < 4; ++mt)
#pragma unroll
      for (int nt = 0; nt < 4; ++nt)
        acc[mt][nt] = __builtin_amdgcn_mfma_f32_16x16x32_bf16(af[mt], bf[nt], acc[mt][nt], 0, 0, 0);
    __syncthreads();
  }
#pragma unroll
  for (int mt = 0; mt < 4; ++mt)
#pragma unroll
    for (int nt = 0; nt < 4; ++nt)
#pragma unroll
      for (int r = 0; r < 4; ++r) {
        size_t idx = (size_t)bzs * zC +
                     (size_t)(bm + wy * 64 + mt * 16 + quad * 4 + r) * N + bn + wx * 64 + nt * 16 + c;
        if (BF16OUT)
          ((unsigned short*)Cv)[idx] = f2bf(acc[mt][nt][r]);
        else
          ((float*)Cv)[idx] = acc[mt][nt][r];
      }
}

// ---- MFMA flash attention: swapped-QK^T, 3-buffer depth-2 counted-vmcnt pipeline.
// Region per tile kt (fenced): [mask bp[kt+1] (1 vmem); fence; stage kt+2 (4 gl_lds)].
// s_waitcnt vmcnt(5) before s_barrier guarantees tile kt's 4 gl_lds complete
// (exactly 5 VMEM ops follow them: next region's 1+4); last tile waits vmcnt(1).
// Prefetch gets 2 tile-computes to land -> barrier never drains to vmcnt(0).
// K LDS: XOR chunk swizzle baked into GLOBAL source (R4-verified).
// V via VP (pre-packed): contiguous staging; PV fragment = one ds_read_b128.
// Row-sum via ones-MFMA; XCD-chunked block swizzle for K/V L2 locality.
__global__ __launch_bounds__(256) void attn_mfma_k(const unsigned short* __restrict__ Q,
                                                   const unsigned short* __restrict__ Kg,
                                                   const unsigned short* __restrict__ VP,
                                                   const unsigned long long* __restrict__ bm,
                                                   unsigned short* __restrict__ O) {
  __shared__ __align__(16) unsigned short Ks[3][64 * 64];
  __shared__ __align__(16) unsigned short Vs[3][64 * 64];
  // XCD-chunked swizzle: XCD k owns 256 consecutive logical blocks (8 (b,h) groups)
  int dlin = (blockIdx.z * NH + blockIdx.y) * (SS / 64) + blockIdx.x;
  int l = (dlin & 7) * 256 + (dlin >> 3);
  int q0 = (l & 31) * 64;
  int h = (l >> 5) & 15;
  int b = l >> 9;
  int tid = threadIdx.x, lane = tid & 63, w = tid >> 6;
  int quad = lane >> 4, c = lane & 15;

  short8 qf[2];
  {
    const unsigned short* qp = Q + ((size_t)b * SS + q0 + w * 16 + c) * DM + h * DK + quad * 8;
    qf[0] = *(const short8*)qp;
    qf[1] = *(const short8*)(qp + 32);
  }
  const unsigned long long* bp = bm + ((size_t)b * SS + q0 + w * 16 + c) * (SS / 64);
  const int shq = quad * 4;

  short8 ones8;
#pragma unroll
  for (int j = 0; j < 8; ++j) ones8[j] = (short)0x3F80;  // bf16 1.0
  const f32x4 z4 = {0.f, 0.f, 0.f, 0.f};

  f32x4 accO[4], lacc;
#pragma unroll
  for (int r = 0; r < 4; ++r) lacc[r] = 0.f;
#pragma unroll
  for (int dt = 0; dt < 4; ++dt)
#pragma unroll
    for (int r = 0; r < 4; ++r) accO[dt][r] = 0.f;

  // K staging source (R4-verified): chunk n=tid (+256): row n>>3, grp (n&7)^(row&7)
  int kr = tid >> 3;
  int scc = (tid & 7) ^ (kr & 7);
  const unsigned short* pK0 = Kg + ((size_t)b * SS + kr) * DM + h * DK + scc * 8;
  const unsigned short* pK1 = pK0 + (size_t)32 * DM;
  const unsigned short* pV0 =
      VP + ((size_t)b * NH + h) * (SS / 64) * 4096 + (size_t)tid * 8;
  const unsigned short* pV1 = pV0 + 2048;

  // QK fragment elem offsets; PV fragment base (R4-proven)
  const int kfo0 = c * 64 + ((quad ^ (c & 7)) * 8);
  const int kfo1 = c * 64 + (((4 + quad) ^ (c & 7)) * 8);
  const int vfbase = quad * 128 + c * 8;

#define MFENCE asm volatile("" ::: "memory")
#define SYNCW(N)                                          \
  do {                                                    \
    asm volatile("s_waitcnt vmcnt(" #N ")" ::: "memory"); \
    __builtin_amdgcn_s_barrier();                         \
    __builtin_amdgcn_sched_barrier(0);                    \
  } while (0)
#define STAGE(i)                                   \
  do {                                             \
    gl_lds16(pK0, &Ks[i][w * 512]);                \
    gl_lds16(pK1, &Ks[i][2048 + w * 512]);         \
    gl_lds16(pV0, &Vs[i][w * 512]);                \
    gl_lds16(pV1, &Vs[i][2048 + w * 512]);         \
    pK0 += (size_t)64 * DM; pK1 += (size_t)64 * DM; \
    pV0 += 4096; pV1 += 4096;                      \
  } while (0)

  unsigned long long mw, mwN;

  auto compute = [&](const unsigned short* KsB, const unsigned short* VsB,
                     unsigned long long mwv) {
    // QK^T swapped: A = K rows, B = Q -> S^T; lane (c,quad) holds S[q=c][k slices]
    f32x4 sacc[4];
    __builtin_amdgcn_s_setprio(1);
#pragma unroll
    for (int nt = 0; nt < 4; ++nt) {
      short8 ka = *(const short8*)&KsB[kfo0 + nt * 1024];
      short8 kb = *(const short8*)&KsB[kfo1 + nt * 1024];
      sacc[nt] = __builtin_amdgcn_mfma_f32_16x16x32_bf16(ka, qf[0], z4, 0, 0, 0);
      sacc[nt] = __builtin_amdgcn_mfma_f32_16x16x32_bf16(kb, qf[1], sacc[nt], 0, 0, 0);
    }
    __builtin_amdgcn_s_setprio(0);

    // in-register softmax numerator (scores pre-scaled by 0.125*log2e via w_q)
    unsigned long long msh = mwv >> shq;
    unsigned mlo = (unsigned)msh, mhi = (unsigned)(msh >> 32);
    unsigned padw[8];
#pragma unroll
    for (int nt = 0; nt < 4; ++nt) {
      unsigned msel = (nt & 2) ? mhi : mlo;
      const int bse = (nt & 1) * 16;
      float pv[4];
#pragma unroll
      for (int r = 0; r < 4; ++r) {
        float ex = fexp2(sacc[nt][r]);
        pv[r] = ((msel >> (bse + r)) & 1u) ? ex : 1.0f;  // masked -> exp(eps) ~ 1
      }
      padw[nt * 2] = cvtpk_bf16(pv[0], pv[1]);
      padw[nt * 2 + 1] = cvtpk_bf16(pv[2], pv[3]);
    }

    // PV: A = lane-local packed P, B = one b128 per fragment (R4-proven layout)
    __builtin_amdgcn_s_setprio(1);
#pragma unroll
    for (int pkt = 0; pkt < 2; ++pkt) {
      union { unsigned u[4]; short8 s8; } pa;
#pragma unroll
      for (int i = 0; i < 4; ++i) pa.u[i] = padw[pkt * 4 + i];
      lacc = __builtin_amdgcn_mfma_f32_16x16x32_bf16(pa.s8, ones8, lacc, 0, 0, 0);
#pragma unroll
      for (int dt = 0; dt < 4; ++dt) {
        short8 vf = *(const short8*)&VsB[(pkt * 4 + dt) * 512 + vfbase];
        accO[dt] = __builtin_amdgcn_mfma_f32_16x16x32_bf16(pa.s8, vf, accO[dt], 0, 0, 0);
      }
    }
    __builtin_amdgcn_s_setprio(0);
  };

  // prologue: fenced order [G(0); M(0); G(1)] so exactly 5 VMEM ops follow G(0)
  STAGE(0);
  MFENCE;
  mw = bp[0];
  MFENCE;
  STAGE(1);

  for (int kt3 = 0; kt3 < 30; kt3 += 3) {
    SYNCW(5); mwN = bp[kt3 + 1]; MFENCE; STAGE(2);
    __builtin_amdgcn_sched_barrier(0);
    compute(&Ks[0][0], &Vs[0][0], mw); mw = mwN;

    SYNCW(5); mwN = bp[kt3 + 2]; MFENCE; STAGE(0);
    __builtin_amdgcn_sched_barrier(0);
    compute(&Ks[1][0], &Vs[1][0], mw); mw = mwN;

    SYNCW(5); mwN = bp[kt3 + 3]; MFENCE; STAGE(1);
    __builtin_amdgcn_sched_barrier(0);
    compute(&Ks[2][0], &Vs[2][0], mw); mw = mwN;
  }
  // kt = 30 (buf0): region = [M(31)] only (no stage; kt+2 = 32)
  SYNCW(5); mwN = bp[31]; MFENCE;
  __builtin_amdgcn_sched_barrier(0);
  compute(&Ks[0][0], &Vs[0][0], mw); mw = mwN;
  // kt = 31 (buf1): only M(31) was issued after G(31) -> vmcnt(1)
  SYNCW(1);
  compute(&Ks[1][0], &Vs[1][0], mw);

#undef MFENCE
#undef SYNCW
#undef STAGE

  // lacc rows (quad*4+r) align with accO rows: direct normalize, no shuffles
  float inv[4];
#pragma unroll
  for (int r = 0; r < 4; ++r) inv[r] = 1.f / lacc[r];
#pragma unroll
  for (int dt = 0; dt < 4; ++dt)
#pragma unroll
    for (int r = 0; r < 4; ++r) {
      int q = q0 + w * 16 + quad * 4 + r;
      O[((size_t)b * SS + q) * DM + h * DK + dt * 16 + c] = f2bf(accO[dt][r] * inv[r]);
    }
}

// ---- Residual + LayerNorm (ddof=1, eps on std), vectorized ----
__global__ __launch_bounds__(256) void ln_k(const float* __restrict__ P,
                                            const float* __restrict__ X,
                                            const float* __restrict__ gamma,
                                            const float* __restrict__ beta,
                                            float* __restrict__ out) {
  __shared__ float sm[4];
  int row = blockIdx.x, tid = threadIdx.x, w = tid >> 6;
  float4 p = ((const float4*)(P + (size_t)row * DM))[tid];
  float4 x = ((const float4*)(X + (size_t)row * DM))[tid];
  float4 v = make_float4(p.x + x.x, p.y + x.y, p.z + x.z, p.w + x.w);
  float s = (v.x + v.y) + (v.z + v.w);
#pragma unroll
  for (int off = 1; off < 64; off <<= 1) s += __shfl_xor(s, off);
  if ((tid & 63) == 0) sm[w] = s;
  __syncthreads();
  float mean = (sm[0] + sm[1] + sm[2] + sm[3]) * (1.f / DM);
  __syncthreads();
  float dx = v.x - mean, dy = v.y - mean, dz = v.z - mean, dw = v.w - mean;
  float s2 = (dx * dx + dy * dy) + (dz * dz + dw * dw);
#pragma unroll
  for (int off = 1; off < 64; off <<= 1) s2 += __shfl_xor(s2, off);
  if ((tid & 63) == 0) sm[w] = s2;
  __syncthreads();
  float var = (sm[0] + sm[1] + sm[2] + sm[3]) * (1.f / (DM - 1));
  float inv = 1.f / (sqrtf(var) + EPSV);
  float4 g = ((const float4*)gamma)[tid];
  float4 be = ((const float4*)beta)[tid];
  float4 y = make_float4(g.x * dx * inv + be.x, g.y * dy * inv + be.y,
                         g.z * dz * inv + be.z, g.w * dw * inv + be.w);
  ((float4*)(out + (size_t)row * DM))[tid] = y;
}

extern "C" void kernel_launch(void* const* d_in, const int* in_sizes, int n_in,
                              void* d_out, int out_size, void* d_ws, size_t ws_size,
                              hipStream_t stream) {
  const float* xq = (const float*)d_in[0];
  const float* xk = (const float*)d_in[1];
  const float* xv = (const float*)d_in[2];
  const int* mask = (const int*)d_in[3];
  const float* wq = (const float*)d_in[4];
  const float* wk = (const float*)d_in[5];
  const float* wv = (const float*)d_in[6];
  const float* w0 = (const float*)d_in[7];
  const float* gamma = (const float*)d_in[8];
  const float* beta = (const float*)d_in[9];
  float* out = (float*)d_out;

  // ws: [xqb NE][xkb NE][xvb NE][wTq MM][wTk MM][wTv MM][wT0 MM][Qb NE][Kb NE][Vb NE][AOb NE]
  // P (f32, NE) overlays Qb+Kb (dead after attention).
  // VP (bf16, NE) overlays xvb (dead after the QKV GEMM).
  unsigned short* xqb = (unsigned short*)d_ws;
  unsigned short* xkb = xqb + NE;
  unsigned short* xvb = xkb + NE;
  unsigned short* wTq = xvb + NE;
  unsigned short* wTk = wTq + MM;
  unsigned short* wTv = wTk + MM;
  unsigned short* wT0 = wTv + MM;
  unsigned short* Qb = wT0 + MM;
  unsigned short* Kb = Qb + NE;
  unsigned short* Vb = Kb + NE;
  unsigned short* AOb = Vb + NE;
  unsigned short* VPb = xvb;  // overlay
  float* P = (float*)Qb;
  unsigned long long* bm = (unsigned long long*)d_out;  // 2 MB, dead before ln_k writes

  const int M = BB * SS;  // 8192
  cvt_x_k<<<(unsigned)(3 * (NE / 4) / 256), 256, 0, stream>>>(xq, xk, xv, xqb, xkb, xvb);
  cvt_wT_k<<<dim3(32, 32, 4), 256, 0, stream>>>(wq, wk, wv, w0, wTq, wTk, wTv, wT0);
  maskbits_k<<<256, 256, 0, stream>>>(mask, bm);
  gemm_lds_k<true><<<dim3(DM / 128, M / 128, 3), 256, 0, stream>>>(
      xqb, wTq, Qb, M, DM, DM, NE, MM, NE, 192);
  vpack_k<<<dim3(SS / 64, NH, BB), 256, 0, stream>>>(Vb, VPb);
  attn_mfma_k<<<dim3(SS / 64, NH, BB), 256, 0, stream>>>(Qb, Kb, VPb, bm, AOb);
  gemm_lds_k<false><<<dim3(DM / 128, M / 128, 1), 256, 0, stream>>>(
      AOb, wT0, P, M, DM, DM, 0, 0, 0, 64);
  ln_k<<<M, 256, 0, stream>>>(P, xq, gamma, beta, out);
}